// Round 1
// 1388.460 us; speedup vs baseline: 1.3927x; 1.3927x over previous
//
#include <hip/hip_runtime.h>
#include <math.h>

// ============================================================================
// R1: split-bf16 MFMA path for the three K=4096 GEMMs (Bmat batch, C7, final).
// ws_size = 2 GiB (confirmed by 2^31-byte harness fills) -> ~170 MB used.
// fp32 x = hi(bf16) + lo(bf16); C = Ah*Bh + Ah*Bl + Al*Bh on matrix cores.
// ============================================================================

typedef unsigned short u16;
typedef __attribute__((ext_vector_type(8))) short bhalf8;   // 8 bf16 = 4 VGPR
typedef __attribute__((ext_vector_type(16))) float f32x16;  // 32x32 mfma acc

__device__ __forceinline__ void split2(float f, unsigned &h, unsigned &l){
  unsigned u = __float_as_uint(f);
  h = u >> 16;                                  // truncated hi bf16
  float r = f - __uint_as_float(u & 0xFFFF0000u); // exact residual
  l = __float_as_uint(r) >> 16;                 // lo bf16
}

// ---------------------------------------------------------------------------
// prep: Q0/Q1 state copies + scorer norms. grid 513 x 256. All fp32.
__launch_bounds__(256)
__global__ void prep_kernel(const float* __restrict__ q0, const float* __restrict__ q1,
                            const float* __restrict__ sc0, const float* __restrict__ sc1,
                            float* __restrict__ q0a, float* __restrict__ q1a,
                            float* __restrict__ sn){
  int b = blockIdx.x, tid = threadIdx.x;
  if (b < 256){ q0a[b*256 + tid] = q0[b*256 + tid]; }
  else if (b < 512){ int r = b - 256; q1a[r*256 + tid] = q1[r*256 + tid]; }
  else {
    __shared__ float s0[256], s1[256];
    float a = sc0[tid]; float c = sc1[tid];
    s0[tid] = a*a; s1[tid] = c*c; __syncthreads();
    for (int off = 128; off > 0; off >>= 1){
      if (tid < off){ s0[tid] += s0[tid+off]; s1[tid] += s1[tid+off]; }
      __syncthreads();
    }
    if (tid == 0){ sn[0] = sqrtf(s0[0]); sn[1] = sqrtf(s1[0]); }
  }
}

// ---------------------------------------------------------------------------
// ts[t][j] = tanh( dot(emb_t[j,:], scorer) / sn ) for j in 0..255
__launch_bounds__(256)
__global__ void scores_kernel(const float* __restrict__ emb, long embStrideT,
                              const float* __restrict__ scorer,
                              const float* __restrict__ sn, int snIdx,
                              float* __restrict__ ts, int tsStrideT){
  int t = blockIdx.y;
  int wave = threadIdx.x >> 6, lane = threadIdx.x & 63;
  int j = blockIdx.x*4 + wave;
  const float* row = emb + (long)t*embStrideT + (long)j*256;
  float s = 0.f;
  for (int c = lane; c < 256; c += 64) s += row[c] * scorer[c];
  for (int off = 32; off > 0; off >>= 1) s += __shfl_down(s, off);
  if (lane == 0) ts[t*tsStrideT + j] = tanhf(s / sn[snIdx]);
}

// ---------------------------------------------------------------------------
// split fp32 -> (hi, lo) bf16, k-contiguous layout preserved. 8 elems/thread.
__launch_bounds__(256)
__global__ void split_kernel(const float* __restrict__ src, long sStride,
                             u16* __restrict__ dh, u16* __restrict__ dl,
                             long dStride, int n8){
  int z = blockIdx.y;
  const float* S = src + (long)z * sStride;
  u16* H = dh + (long)z * dStride;
  u16* L = dl + (long)z * dStride;
  int i = blockIdx.x * 256 + threadIdx.x;
  if (i >= n8) return;
  long o = (long)i * 8;
  float4 v0 = *(const float4*)(S + o);
  float4 v1 = *(const float4*)(S + o + 4);
  unsigned h0,h1,h2,h3,h4,h5,h6,h7, l0,l1,l2,l3,l4,l5,l6,l7;
  split2(v0.x,h0,l0); split2(v0.y,h1,l1); split2(v0.z,h2,l2); split2(v0.w,h3,l3);
  split2(v1.x,h4,l4); split2(v1.y,h5,l5); split2(v1.z,h6,l6); split2(v1.w,h7,l7);
  uint4 ph, pl;
  ph.x = h0 | (h1<<16); ph.y = h2 | (h3<<16); ph.z = h4 | (h5<<16); ph.w = h6 | (h7<<16);
  pl.x = l0 | (l1<<16); pl.y = l2 | (l3<<16); pl.z = l4 | (l5<<16); pl.w = l6 | (l7<<16);
  *(uint4*)(H + o) = ph;
  *(uint4*)(L + o) = pl;
}

// ---------------------------------------------------------------------------
// transpose + split: src fp32 [4096][256] -> dst hi/lo bf16 [256][4096].
// 32x32 tiles via LDS (stride 33 -> conflict-free both phases).
__launch_bounds__(256)
__global__ void tconv_kernel(const float* __restrict__ src, long sStride,
                             u16* __restrict__ dh, u16* __restrict__ dl, long dStride){
  int z = blockIdx.z;
  const float* S = src + (long)z * sStride;
  u16* H = dh + (long)z * dStride;
  u16* L = dl + (long)z * dStride;
  int k0 = blockIdx.x << 5, n0 = blockIdx.y << 5;
  int c = threadIdx.x & 31, r = threadIdx.x >> 5;   // r 0..7
  __shared__ float s[32][33];
  #pragma unroll
  for (int i = 0; i < 4; i++)
    s[r + 8*i][c] = S[(long)(k0 + r + 8*i) * 256 + n0 + c];
  __syncthreads();
  #pragma unroll
  for (int i = 0; i < 4; i++){
    int rr = r + 8*i;
    unsigned h, l;
    split2(s[c][rr], h, l);
    H[(long)(n0 + rr) * 4096 + k0 + c] = (u16)h;
    L[(long)(n0 + rr) * 4096 + k0 + c] = (u16)l;
  }
}

// ---------------------------------------------------------------------------
// split-bf16 MFMA GEMM, K=4096 fixed, split-K=4 -> partials.
// A hi/lo: [M][4096] bf16 row-major. B hi/lo: [256][4096] bf16 (= B^T, k-contig).
// Block tile 128x128 (BK=64), 4 waves, wave tile 64x64, mfma_f32_32x32x16_bf16.
// grid: (M/128, 2, z*4+ks). Partials P[z][ks][M][256] fp32.
// LDS tiles are [128 rows][64 k] bf16 (128 B rows): 16B-granule XOR swizzle
// (byte ^= (row&7)<<4) breaks the 32-way conflict on fragment ds_read_b128;
// staging writes use the same XOR (full 8-row spans -> conflict-free writes).
__device__ __forceinline__ int swzA(int row, int kb){
  return (row << 7) + (kb ^ ((row & 7) << 4));
}

__launch_bounds__(256, 2)
__global__ void gemm_mfma(const u16* __restrict__ Ah, const u16* __restrict__ Al, long aStride,
                          const u16* __restrict__ Bh, const u16* __restrict__ Bl, long bStride,
                          float* __restrict__ P, long pStride){
  int mt = blockIdx.x, nt = blockIdx.y;
  int z = blockIdx.z >> 2, ks = blockIdx.z & 3;
  long M256 = (long)gridDim.x * 32768;     // 128*256 per m-tile
  const u16* ah = Ah + (long)z * aStride;
  const u16* al = Al + (long)z * aStride;
  const u16* bh = Bh + (long)z * bStride;
  const u16* bl = Bl + (long)z * bStride;
  float* pout = P + (long)z * pStride + (long)ks * M256;

  __shared__ u16 lds[32768];               // 64 KB: Ah,Al,Bh,Bl tiles 128x64
  u16* sAh = lds;
  u16* sAl = lds + 8192;
  u16* sBh = lds + 16384;
  u16* sBl = lds + 24576;

  int tid  = threadIdx.x;
  int lane = tid & 63, wave = tid >> 6;
  int wm = (wave >> 1) << 6, wn = (wave & 1) << 6;  // wave tile origin
  int ln31 = lane & 31, lhi = lane >> 5;

  int m0 = mt << 7, n0 = nt << 7;
  int srow = tid >> 3;                     // 0..31 (staging row within pass)
  int skE  = (tid & 7) << 3;               // staging k-elem offset (x8 = 16 B)

  f32x16 acc00, acc01, acc10, acc11;
  #pragma unroll
  for (int i = 0; i < 16; i++){ acc00[i]=0.f; acc01[i]=0.f; acc10[i]=0.f; acc11[i]=0.f; }

  long kbase = (long)ks << 10;             // K chunk of 1024
  for (int kk = 0; kk < 16; kk++){
    long k0 = kbase + ((long)kk << 6);
    // ---- stage 64 KB (4 tiles) : 16 x uint4 loads then 16 LDS writes ----
    uint4 ra[4], rb[4], rc[4], rd[4];
    #pragma unroll
    for (int p = 0; p < 4; p++){
      int row = (p << 5) + srow;
      long ga = (long)(m0 + row) * 4096 + k0 + skE;
      long gb = (long)(n0 + row) * 4096 + k0 + skE;
      ra[p] = *(const uint4*)(ah + ga);
      rb[p] = *(const uint4*)(al + ga);
      rc[p] = *(const uint4*)(bh + gb);
      rd[p] = *(const uint4*)(bl + gb);
    }
    #pragma unroll
    for (int p = 0; p < 4; p++){
      int row = (p << 5) + srow;
      int lo = swzA(row, skE << 1);
      *(uint4*)((char*)sAh + lo) = ra[p];
      *(uint4*)((char*)sAl + lo) = rb[p];
      *(uint4*)((char*)sBh + lo) = rc[p];
      *(uint4*)((char*)sBl + lo) = rd[p];
    }
    __syncthreads();
    // ---- compute: 4 k16 steps x 12 mfma ----
    #pragma unroll
    for (int s = 0; s < 4; s++){
      int kb = (s << 5) + (lhi << 4);      // byte offset of this lane's 8 elems
      bhalf8 a0h = *(const bhalf8*)((char*)sAh + swzA(wm + ln31,      kb));
      bhalf8 a1h = *(const bhalf8*)((char*)sAh + swzA(wm + 32 + ln31, kb));
      bhalf8 a0l = *(const bhalf8*)((char*)sAl + swzA(wm + ln31,      kb));
      bhalf8 a1l = *(const bhalf8*)((char*)sAl + swzA(wm + 32 + ln31, kb));
      bhalf8 b0h = *(const bhalf8*)((char*)sBh + swzA(wn + ln31,      kb));
      bhalf8 b1h = *(const bhalf8*)((char*)sBh + swzA(wn + 32 + ln31, kb));
      bhalf8 b0l = *(const bhalf8*)((char*)sBl + swzA(wn + ln31,      kb));
      bhalf8 b1l = *(const bhalf8*)((char*)sBl + swzA(wn + 32 + ln31, kb));
      // product-major order: same-acc reuse distance 4
      acc00 = __builtin_amdgcn_mfma_f32_32x32x16_bf16(a0h, b0h, acc00, 0, 0, 0);
      acc01 = __builtin_amdgcn_mfma_f32_32x32x16_bf16(a0h, b1h, acc01, 0, 0, 0);
      acc10 = __builtin_amdgcn_mfma_f32_32x32x16_bf16(a1h, b0h, acc10, 0, 0, 0);
      acc11 = __builtin_amdgcn_mfma_f32_32x32x16_bf16(a1h, b1h, acc11, 0, 0, 0);
      acc00 = __builtin_amdgcn_mfma_f32_32x32x16_bf16(a0h, b0l, acc00, 0, 0, 0);
      acc01 = __builtin_amdgcn_mfma_f32_32x32x16_bf16(a0h, b1l, acc01, 0, 0, 0);
      acc10 = __builtin_amdgcn_mfma_f32_32x32x16_bf16(a1h, b0l, acc10, 0, 0, 0);
      acc11 = __builtin_amdgcn_mfma_f32_32x32x16_bf16(a1h, b1l, acc11, 0, 0, 0);
      acc00 = __builtin_amdgcn_mfma_f32_32x32x16_bf16(a0l, b0h, acc00, 0, 0, 0);
      acc01 = __builtin_amdgcn_mfma_f32_32x32x16_bf16(a0l, b1h, acc01, 0, 0, 0);
      acc10 = __builtin_amdgcn_mfma_f32_32x32x16_bf16(a1l, b0h, acc10, 0, 0, 0);
      acc11 = __builtin_amdgcn_mfma_f32_32x32x16_bf16(a1l, b1h, acc11, 0, 0, 0);
    }
    __syncthreads();
  }
  // ---- epilogue: D layout col=lane&31, row=(reg&3)+8*(reg>>2)+4*(lane>>5) ----
  float* po = pout + (long)(m0 + wm) * 256 + (n0 + wn);
  int rb16 = lhi << 2;
  #pragma unroll
  for (int reg = 0; reg < 16; reg++){
    int r = (reg & 3) + ((reg >> 2) << 3) + rb16;
    po[(long)r * 256 + ln31]              = acc00[reg];
    po[(long)r * 256 + 32 + ln31]         = acc01[reg];
    po[(long)(r + 32) * 256 + ln31]       = acc10[reg];
    po[(long)(r + 32) * 256 + 32 + ln31]  = acc11[reg];
  }
}

// ---------------------------------------------------------------------------
// sum the 4 split-K partials (+optional relu). float4 per thread.
__launch_bounds__(256)
__global__ void reduce4_kernel(const float* __restrict__ P, long zStrideP, long ksStride,
                               float* __restrict__ out, long zStrideO, int count4, int relu){
  int z = blockIdx.y;
  const float* p = P + (long)z * zStrideP;
  float* o = out + (long)z * zStrideO;
  int i = blockIdx.x * 256 + threadIdx.x;
  if (i >= count4) return;
  long b = (long)i * 4;
  float4 v0 = *(const float4*)(p + b);
  float4 v1 = *(const float4*)(p + ksStride + b);
  float4 v2 = *(const float4*)(p + 2*ksStride + b);
  float4 v3 = *(const float4*)(p + 3*ksStride + b);
  float4 r;
  r.x = v0.x+v1.x+v2.x+v3.x; r.y = v0.y+v1.y+v2.y+v3.y;
  r.z = v0.z+v1.z+v2.z+v3.z; r.w = v0.w+v1.w+v2.w+v3.w;
  if (relu){ r.x=fmaxf(r.x,0.f); r.y=fmaxf(r.y,0.f); r.z=fmaxf(r.z,0.f); r.w=fmaxf(r.w,0.f); }
  *(float4*)(o + b) = r;
}

// ---------------------------------------------------------------------------
// Gates (unchanged): W@zt (+U@Q+b, sigmoid) for z,r; raw Wh@zt for h.
__launch_bounds__(256)
__global__ void gates_kernel(const float* __restrict__ emb,
                             const float* __restrict__ Wz, const float* __restrict__ Wr, const float* __restrict__ Wh,
                             const float* __restrict__ Uz, const float* __restrict__ Ur,
                             const float* __restrict__ bz, const float* __restrict__ br,
                             const float* __restrict__ Qcur, const float* __restrict__ ts,
                             float* __restrict__ G){
  int bx = blockIdx.x;
  int g = bx >> 6, tile = bx & 63;
  int m0 = (tile >> 3) << 5, j0 = (tile & 7) << 5;
  const float* W = (g==0) ? Wz : (g==1) ? Wr : Wh;
  int tid = threadIdx.x, tx = tid & 15, ty = tid >> 4;
  int rs = tid >> 3, cs = (tid & 7) << 2;
  __shared__ float sA[32][33];
  __shared__ float sB[32][33];
  float a00=0,a01=0,a10=0,a11=0;
  for (int k0 = 0; k0 < 256; k0 += 32){
    const float* pw = W   + (m0+rs)*256 + k0 + cs;
    const float* pe = emb + (long)(j0+rs)*256 + k0 + cs;
    sA[rs][cs+0]=pw[0]; sA[rs][cs+1]=pw[1]; sA[rs][cs+2]=pw[2]; sA[rs][cs+3]=pw[3];
    sB[cs+0][rs]=pe[0]; sB[cs+1][rs]=pe[1]; sB[cs+2][rs]=pe[2]; sB[cs+3][rs]=pe[3];
    __syncthreads();
    #pragma unroll
    for (int k = 0; k < 32; k++){
      float x0=sA[ty][k], x1=sA[ty+16][k], y0=sB[k][tx], y1=sB[k][tx+16];
      a00 += x0*y0; a01 += x0*y1; a10 += x1*y0; a11 += x1*y1;
    }
    __syncthreads();
  }
  float t0 = ts[j0+tx], t1 = ts[j0+tx+16];
  a00*=t0; a10*=t0; a01*=t1; a11*=t1;
  if (g == 2){
    G[2*65536 + (m0+ty   )*256 + j0+tx   ] = a00;
    G[2*65536 + (m0+ty   )*256 + j0+tx+16] = a01;
    G[2*65536 + (m0+ty+16)*256 + j0+tx   ] = a10;
    G[2*65536 + (m0+ty+16)*256 + j0+tx+16] = a11;
    return;
  }
  const float* U  = (g==0) ? Uz : Ur;
  const float* bb = (g==0) ? bz : br;
  float u00=0,u01=0,u10=0,u11=0;
  for (int k0 = 0; k0 < 256; k0 += 32){
    const float* pu = U    + (m0+rs)*256 + k0 + cs;
    const float* pq = Qcur + (k0+rs)*256 + j0 + cs;
    sA[rs][cs+0]=pu[0]; sA[rs][cs+1]=pu[1]; sA[rs][cs+2]=pu[2]; sA[rs][cs+3]=pu[3];
    sB[rs][cs+0]=pq[0]; sB[rs][cs+1]=pq[1]; sB[rs][cs+2]=pq[2]; sB[rs][cs+3]=pq[3];
    __syncthreads();
    #pragma unroll
    for (int k = 0; k < 32; k++){
      float x0=sA[ty][k], x1=sA[ty+16][k], y0=sB[k][tx], y1=sB[k][tx+16];
      u00 += x0*y0; u01 += x0*y1; u10 += x1*y0; u11 += x1*y1;
    }
    __syncthreads();
  }
  int m = m0+ty, j = j0+tx;
  float v;
  v = a00+u00+bb[m*256+j];          G[g*65536 + m*256+j]          = 1.f/(1.f+__expf(-v));
  v = a01+u01+bb[m*256+j+16];       G[g*65536 + m*256+j+16]       = 1.f/(1.f+__expf(-v));
  v = a10+u10+bb[(m+16)*256+j];     G[g*65536 + (m+16)*256+j]     = 1.f/(1.f+__expf(-v));
  v = a11+u11+bb[(m+16)*256+j+16];  G[g*65536 + (m+16)*256+j+16]  = 1.f/(1.f+__expf(-v));
}

// ---------------------------------------------------------------------------
// Update (unchanged): Qnew = (1-z)*Q + z*tanh( Uh@(rst*Q) + G[2] + bh ).
__launch_bounds__(256)
__global__ void update_kernel(const float* __restrict__ Uh, const float* __restrict__ bh,
                              const float* __restrict__ G, const float* __restrict__ Qcur,
                              float* __restrict__ Qnew){
  int tile = blockIdx.x;
  int m0 = (tile >> 3) << 5, j0 = (tile & 7) << 5;
  int tid = threadIdx.x, tx = tid & 15, ty = tid >> 4;
  int rs = tid >> 3, cs = (tid & 7) << 2;
  __shared__ float sA[32][33];
  __shared__ float sB[32][33];
  float a00=0,a01=0,a10=0,a11=0;
  for (int k0 = 0; k0 < 256; k0 += 32){
    const float* pu = Uh + (m0+rs)*256 + k0 + cs;
    const float* pr = G + 65536 + (k0+rs)*256 + j0 + cs;
    const float* pq = Qcur      + (k0+rs)*256 + j0 + cs;
    sA[rs][cs+0]=pu[0]; sA[rs][cs+1]=pu[1]; sA[rs][cs+2]=pu[2]; sA[rs][cs+3]=pu[3];
    sB[rs][cs+0]=pr[0]*pq[0]; sB[rs][cs+1]=pr[1]*pq[1]; sB[rs][cs+2]=pr[2]*pq[2]; sB[rs][cs+3]=pr[3]*pq[3];
    __syncthreads();
    #pragma unroll
    for (int k = 0; k < 32; k++){
      float x0=sA[ty][k], x1=sA[ty+16][k], y0=sB[k][tx], y1=sB[k][tx+16];
      a00 += x0*y0; a01 += x0*y1; a10 += x1*y0; a11 += x1*y1;
    }
    __syncthreads();
  }
  #pragma unroll
  for (int ii = 0; ii < 2; ii++){
    #pragma unroll
    for (int jj = 0; jj < 2; jj++){
      float acc = (ii==0) ? (jj==0?a00:a01) : (jj==0?a10:a11);
      int m = m0 + ty + ii*16, j = j0 + tx + jj*16;
      float h = tanhf(acc + G[2*65536 + m*256 + j] + bh[m*256+j]);
      float z = G[m*256 + j];
      float q = Qcur[m*256 + j];
      Qnew[m*256 + j] = (1.f - z)*q + z*h;
    }
  }
}

// ---------------------------------------------------------------------------
// Small fp32 GEMM (unchanged), K=256. Used for H1 = relu(Bm @ Q) and Z = H1 @ Q1.
__launch_bounds__(256)
__global__ void small_gemm_kernel(const float* __restrict__ Am, const float* __restrict__ Bm,
                                  float* __restrict__ C, int relu){
  int bx = blockIdx.x;
  int m0 = (bx >> 3) << 5, j0 = (bx & 7) << 5;
  int tid = threadIdx.x, tx = tid & 15, ty = tid >> 4;
  int rs = tid >> 3, cs = (tid & 7) << 2;
  __shared__ float sA[32][33];
  __shared__ float sB[32][33];
  float a00=0,a01=0,a10=0,a11=0;
  for (int k0 = 0; k0 < 256; k0 += 32){
    const float* pa = Am + (long)(m0+rs)*256 + k0 + cs;
    const float* pb = Bm + (long)(k0+rs)*256 + j0 + cs;
    sA[rs][cs+0]=pa[0]; sA[rs][cs+1]=pa[1]; sA[rs][cs+2]=pa[2]; sA[rs][cs+3]=pa[3];
    sB[rs][cs+0]=pb[0]; sB[rs][cs+1]=pb[1]; sB[rs][cs+2]=pb[2]; sB[rs][cs+3]=pb[3];
    __syncthreads();
    #pragma unroll
    for (int k = 0; k < 32; k++){
      float x0=sA[ty][k], x1=sA[ty+16][k], y0=sB[k][tx], y1=sB[k][tx+16];
      a00 += x0*y0; a01 += x0*y1; a10 += x1*y0; a11 += x1*y1;
    }
    __syncthreads();
  }
  if (relu){ a00=fmaxf(a00,0.f); a01=fmaxf(a01,0.f); a10=fmaxf(a10,0.f); a11=fmaxf(a11,0.f); }
  C[(long)(m0+ty   )*256 + j0+tx   ] = a00;
  C[(long)(m0+ty   )*256 + j0+tx+16] = a01;
  C[(long)(m0+ty+16)*256 + j0+tx   ] = a10;
  C[(long)(m0+ty+16)*256 + j0+tx+16] = a11;
}

// ---------------------------------------------------------------------------
extern "C" void kernel_launch(void* const* d_in, const int* in_sizes, int n_in,
                              void* d_out, int out_size, void* d_ws, size_t ws_size,
                              hipStream_t stream){
  (void)in_sizes; (void)n_in; (void)out_size; (void)ws_size;
  const int N = 4096, F = 256;

  const float* A = (const float*)d_in[0];
  const float* X = (const float*)d_in[1];
  const float *SC[2], *WZ[2], *UZ[2], *BZ[2], *WR[2], *UR[2], *BR[2], *WH[2], *UH[2], *BH[2], *Q0I[2];
  for (int l = 0; l < 2; l++){
    int b = 3 + l*11;
    SC[l]  = (const float*)d_in[b+0];
    WZ[l]  = (const float*)d_in[b+1];  UZ[l] = (const float*)d_in[b+2];  BZ[l] = (const float*)d_in[b+3];
    WR[l]  = (const float*)d_in[b+4];  UR[l] = (const float*)d_in[b+5];  BR[l] = (const float*)d_in[b+6];
    WH[l]  = (const float*)d_in[b+7];  UH[l] = (const float*)d_in[b+8];  BH[l] = (const float*)d_in[b+9];
    Q0I[l] = (const float*)d_in[b+10];
  }

  char* w = (char*)d_ws;
  float* sn   = (float*)(w);                 // 2 floats (1 KiB slot)
  float* q0a  = (float*)(w + 1024);          // 256x256 fp32 x4 (ping-pong)
  float* q0b  = q0a + 65536;
  float* q1a  = q0b + 65536;
  float* q1b  = q1a + 65536;
  float* ts0  = q1b + 65536;                 // 8*256
  float* ts1  = ts0 + 2048;                  // 256
  float* G    = ts1 + 256;                   // 3*65536
  float* Bmat = G + 3*65536;                 // 7*65536
  float* C7   = Bmat + 7*65536;              // 4096*256
  float* H1   = C7 + 1048576;                // 4096*256
  float* Z    = C7;                          // alias: C7 dead after t=7 h1
  // ---- R1 additions (all 16B-aligned by construction) ----
  u16* A7H = (u16*)(H1 + 1048576);           // [4096][4096] hi
  u16* A7L = A7H + 16777216;                 // lo
  u16* ArH = A7L + 16777216;                 // [7][256][4096] hi
  u16* ArL = ArH + 7340032;                  // lo
  u16* XtH = ArL + 7340032;                  // [8][256][4096] hi (X^T per t)
  u16* XtL = XtH + 8388608;                  // lo
  u16* ZtH = XtL + 8388608;                  // [256][4096] hi (Z^T)
  u16* ZtL = ZtH + 1048576;                  // lo
  float* PB = (float*)(ZtL + 1048576);       // [7][4][256][256] partials
  float* PC = PB + 1835008;                  // [4][4096][256] partials (C7 & final)
  // total ~170 MB of the 2 GiB workspace

  // ---- parallel pre-phase ----
  prep_kernel<<<513, 256, 0, stream>>>(Q0I[0], Q0I[1], SC[0], SC[1], q0a, q1a, sn);
  scores_kernel<<<dim3(64, 8), 256, 0, stream>>>(X, (long)N*F, SC[0], sn, 0, ts0, 256);
  // split A_7 (full) and A_t[:256] (t<7) into hi/lo bf16
  split_kernel<<<dim3(8192, 1), 256, 0, stream>>>(A + (long)7*N*N, 0, A7H, A7L, 0, 2097152);
  split_kernel<<<dim3(512, 7), 256, 0, stream>>>(A, (long)N*N, ArH, ArL, 1048576, 131072);
  // transpose+split all X_t -> [256][4096]
  tconv_kernel<<<dim3(128, 8, 8), 256, 0, stream>>>(X, 1048576, XtH, XtL, 1048576);
  // Bmat_t = A_t[:256] @ X_t  (t=0..6), split-K=4 partials
  gemm_mfma<<<dim3(2, 2, 28), 256, 0, stream>>>(ArH, ArL, 1048576, XtH, XtL, 1048576, PB, 262144);
  // C7 = A_7 @ X_7
  gemm_mfma<<<dim3(32, 2, 4), 256, 0, stream>>>(A7H, A7L, 0, XtH + 7*1048576, XtL + 7*1048576, 0, PC, 0);
  reduce4_kernel<<<dim3(64, 7), 256, 0, stream>>>(PB, 262144, 65536, Bmat, 65536, 16384, 0);
  reduce4_kernel<<<dim3(1024, 1), 256, 0, stream>>>(PC, 0, 1048576, C7, 0, 262144, 0);

  // ---- sequential scan (both layers interleaved, unchanged) ----
  float *q0c = q0a, *q0n = q0b, *q1c = q1a, *q1n = q1b;
  for (int t = 0; t < 8; t++){
    gates_kernel<<<192, 256, 0, stream>>>(X + (long)t*N*F, WZ[0], WR[0], WH[0], UZ[0], UR[0],
                                          BZ[0], BR[0], q0c, ts0 + t*256, G);
    update_kernel<<<64, 256, 0, stream>>>(UH[0], BH[0], G, q0c, q0n);
    if (t < 7) small_gemm_kernel<<<64,   256, 0, stream>>>(Bmat + t*65536, q0n, H1, 1);
    else       small_gemm_kernel<<<1024, 256, 0, stream>>>(C7, q0n, H1, 1);
    scores_kernel<<<dim3(64, 1), 256, 0, stream>>>(H1, 0, SC[1], sn, 1, ts1, 0);
    gates_kernel<<<192, 256, 0, stream>>>(H1, WZ[1], WR[1], WH[1], UZ[1], UR[1],
                                          BZ[1], BR[1], q1c, ts1, G);
    update_kernel<<<64, 256, 0, stream>>>(UH[1], BH[1], G, q1c, q1n);
    float* tmp;
    tmp = q0c; q0c = q0n; q0n = tmp;
    tmp = q1c; q1c = q1n; q1n = tmp;
  }

  // ---- final output: out = relu(A_7 @ (H1_7 @ Q1)) ----
  small_gemm_kernel<<<1024, 256, 0, stream>>>(H1, q1c, Z, 0);
  tconv_kernel<<<dim3(128, 8, 1), 256, 0, stream>>>(Z, 0, ZtH, ZtL, 0);
  gemm_mfma<<<dim3(32, 2, 4), 256, 0, stream>>>(A7H, A7L, 0, ZtH, ZtL, 0, PC, 0);
  reduce4_kernel<<<dim3(1024, 1), 256, 0, stream>>>(PC, 0, 1048576, (float*)d_out, 0, 262144, 1);
}